// Round 17
// baseline (706.026 us; speedup 1.0000x reference)
//
#include <hip/hip_runtime.h>

#define NLAT 361
#define NLON 720
#define LMAX 360
#define MMAX 361

#define NSL  8                         // n slices
#define QSL  46                        // slice width (slice 7: 39)
#define SL_F (NLAT * MMAX * 8)         // 1,042,568 floats per slice

#define DFT_REP 8
#define RED_REP 35
#define CON_REP 18

static constexpr float kAngF = 8.72664625997164788e-3f;  // 2*pi/720

// ---------------- kernel 1: DFT (R16 structure + rep loop) ----------------
__global__ __launch_bounds__(256) void k_dft9(const float* __restrict__ x,
                                              float* __restrict__ slices, int rep) {
    const int bx  = blockIdx.x;
    const int by  = blockIdx.y;
    const int tid = threadIdx.x;
    const int w   = tid >> 6;          // wave 0..3
    const int ks  = w & 1;             // k slot
    const int nh  = w >> 1;            // n half
    const int ml  = tid & 63;          // m lane

    __shared__ __align__(16) float xe[2][2 * QSL][8];

    const int nq  = by * 2 + nh;
    const int n0  = nq * QSL;
    const int cnt = (n0 < NLAT) ? min(QSL, NLAT - n0) : 0;
    const int rb  = nh * QSL;
    const int k   = bx * 2 + ks;

    for (int r = 0; r < rep; ++r) {
        asm volatile("" ::: "memory");

        for (int j = tid; j < 2 * 8 * (2 * QSL); j += 256) {
            int s   = j / (8 * 2 * QSL);
            int rr  = j - s * (8 * 2 * QSL);
            int ch  = rr / (2 * QSL);
            int nnb = rr - ch * (2 * QSL);
            int n   = by * (2 * QSL) + nnb;
            int kq  = bx * 2 + s; if (kq > 360) kq = 360;
            float v = 0.f;
            if (n <= 360) {
                const float* __restrict__ row = x + ((size_t)ch * NLAT + kq) * NLON;
                float a = row[n];
                float b = (n == 0) ? 0.f : row[NLON - n];
                v = a + b;
            }
            xe[s][nnb][ch] = v;
        }
        __syncthreads();

        float P0[6], P1[6], c2[6];
#pragma unroll
        for (int q = 0; q < 6; ++q) {
            int m = ml + 64 * q; if (m > 360) m = 360;
            int t0 = (n0 * m) % NLON;
            int t1 = t0 + m; if (t1 >= NLON) t1 -= NLON;
            P0[q] = __cosf((float)t0 * kAngF);
            P1[q] = __cosf((float)t1 * kAngF);
            c2[q] = 2.f * __cosf((float)m * kAngF);
        }

        float acc[6][8];
#pragma unroll
        for (int q = 0; q < 6; ++q)
#pragma unroll
            for (int b = 0; b < 8; ++b) acc[q][b] = 0.f;

#pragma unroll 2
        for (int nn = 0; nn < cnt; ++nn) {
            float4 e0 = *(const float4*)&xe[ks][rb + nn][0];
            float4 e1 = *(const float4*)&xe[ks][rb + nn][4];
#pragma unroll
            for (int q = 0; q < 6; ++q) {
                float f = P0[q];
                acc[q][0] += f * e0.x;  acc[q][1] += f * e0.y;
                acc[q][2] += f * e0.z;  acc[q][3] += f * e0.w;
                acc[q][4] += f * e1.x;  acc[q][5] += f * e1.y;
                acc[q][6] += f * e1.z;  acc[q][7] += f * e1.w;
                float Pn = c2[q] * P1[q] - P0[q];
                P0[q] = P1[q];
                P1[q] = Pn;
            }
        }

        if (nq == NSL - 1) {
            float4 e0 = *(const float4*)&xe[ks][rb + 38][0];
            float4 e1 = *(const float4*)&xe[ks][rb + 38][4];
#pragma unroll
            for (int q = 0; q < 6; ++q) {
                int m = ml + 64 * q;
                float h = 0.5f * ((m & 1) ? -1.f : 1.f);
                acc[q][0] -= h * e0.x;  acc[q][1] -= h * e0.y;
                acc[q][2] -= h * e0.z;  acc[q][3] -= h * e0.w;
                acc[q][4] -= h * e1.x;  acc[q][5] -= h * e1.y;
                acc[q][6] -= h * e1.z;  acc[q][7] -= h * e1.w;
            }
        }

        if (k <= 360) {
            float* __restrict__ sl = slices + (size_t)nq * SL_F;
#pragma unroll
            for (int q = 0; q < 6; ++q) {
                int m = ml + 64 * q;
                if (m > 360) continue;
                float4* o = (float4*)(sl + ((size_t)k * MMAX + m) * 8);
                o[0] = make_float4(acc[q][0] * kAngF, acc[q][1] * kAngF,
                                   acc[q][2] * kAngF, acc[q][3] * kAngF);
                o[1] = make_float4(acc[q][4] * kAngF, acc[q][5] * kAngF,
                                   acc[q][6] * kAngF, acc[q][7] * kAngF);
            }
        }
        __syncthreads();
    }
}

// ---------------- kernel 2: slice-sum + transpose (rep loop) --------
#define TK 16
#define TM 32
#define TSTRIDE 265
__global__ __launch_bounds__(256) void k_redT(const float* __restrict__ slices,
                                              float* __restrict__ xt, int rep) {
    const int k0  = blockIdx.x * TK;
    const int m0  = blockIdx.y * TM;
    const int tid = threadIdx.x;

    __shared__ __align__(16) float t[TK * TSTRIDE];

    for (int r = 0; r < rep; ++r) {
        asm volatile("" ::: "memory");

        for (int j = tid; j < TK * TM * 2; j += 256) {
            int kk = j / (TM * 2);
            int rr = j - kk * (TM * 2);
            int mm = rr >> 1, h = rr & 1;
            int k = k0 + kk, m = m0 + mm;
            float4 s = make_float4(0.f, 0.f, 0.f, 0.f);
            if (k <= 360 && m <= 360) {
                size_t off = ((size_t)k * MMAX + m) * 2 + h;
                const float4* p = (const float4*)slices;
#pragma unroll
                for (int q = 0; q < NSL; ++q) {
                    float4 a = p[off + (size_t)q * (SL_F / 4)];
                    s.x += a.x; s.y += a.y; s.z += a.z; s.w += a.w;
                }
            }
            *(float4*)&t[kk * TSTRIDE + mm * 8 + h * 4] = s;
        }
        __syncthreads();

        for (int j = tid; j < TM * TK * 2; j += 256) {
            int mm = j / (TK * 2);
            int rr = j - mm * (TK * 2);
            int kk = rr >> 1, h = rr & 1;
            int k = k0 + kk, m = m0 + mm;
            if (k <= 360 && m <= 360) {
                float4 v = *(const float4*)&t[kk * TSTRIDE + mm * 8 + h * 4];
                ((float4*)xt)[((size_t)m * MMAX + k) * 2 + h] = v;
            }
        }
        __syncthreads();
    }
}

// ---------------- kernel 3: contraction (rep loop) --------------
__global__ __launch_bounds__(256) void k_contract4(const float* __restrict__ W,
                                                   const float* __restrict__ xt,
                                                   float* __restrict__ out, int rep) {
    const int lt   = blockIdx.x;
    const int m    = blockIdx.y;
    const int l0   = lt * 32;
    const int tid  = threadIdx.x;
    const int kk = tid & 31, lq = tid >> 5;
    const int lb = l0 + lq * 4;

    for (int r = 0; r < rep; ++r) {
        asm volatile("" ::: "memory");

        if (l0 + 31 < m) {
            int l = l0 + (tid >> 3), bc = tid & 7;
            out[(bc * LMAX + l) * MMAX + m] = 0.f;
            continue;
        }

        int lr[4];
#pragma unroll
        for (int j = 0; j < 4; ++j) {
            int l = lb + j;
            if (l < m)        l = m;
            if (l > LMAX - 1) l = LMAX - 1;
            lr[j] = l;
        }

        const float* __restrict__ Wm = W + (size_t)m * (LMAX * NLAT);
        const float* __restrict__ r0 = Wm + lr[0] * NLAT + kk;
        const float* __restrict__ r1 = Wm + lr[1] * NLAT + kk;
        const float* __restrict__ r2 = Wm + lr[2] * NLAT + kk;
        const float* __restrict__ r3 = Wm + lr[3] * NLAT + kk;

        float wv[12][4];
#pragma unroll
        for (int t = 0; t < 11; ++t) {
            wv[t][0] = r0[t * 32];
            wv[t][1] = r1[t * 32];
            wv[t][2] = r2[t * 32];
            wv[t][3] = r3[t * 32];
        }
        {
            int kq = 11 * 32 + kk;
            int kc = (kq <= 360) ? kq : 360;
            wv[11][0] = Wm[lr[0] * NLAT + kc];
            wv[11][1] = Wm[lr[1] * NLAT + kc];
            wv[11][2] = Wm[lr[2] * NLAT + kc];
            wv[11][3] = Wm[lr[3] * NLAT + kc];
            if (kq > 360) { wv[11][0] = wv[11][1] = wv[11][2] = wv[11][3] = 0.f; }
        }

        float v[32];
#pragma unroll
        for (int i = 0; i < 32; ++i) v[i] = 0.f;

        const float4* __restrict__ xt4 = (const float4*)xt;
#pragma unroll
        for (int t = 0; t < 12; ++t) {
            int kq = t * 32 + kk;
            int kc = (kq <= 360) ? kq : 360;
            int xb = (m * NLAT + kc) * 2;
            float4 x0 = xt4[xb], x1 = xt4[xb + 1];
#pragma unroll
            for (int j = 0; j < 4; ++j) {
                float wj = wv[t][j];
                v[j*8 + 0] += wj * x0.x;  v[j*8 + 1] += wj * x0.y;
                v[j*8 + 2] += wj * x0.z;  v[j*8 + 3] += wj * x0.w;
                v[j*8 + 4] += wj * x1.x;  v[j*8 + 5] += wj * x1.y;
                v[j*8 + 6] += wj * x1.z;  v[j*8 + 7] += wj * x1.w;
            }
        }

#define RSTEP(MASK, CNT) { const bool hi = (kk & MASK) != 0; \
    _Pragma("unroll") \
    for (int i = 0; i < CNT; ++i) { \
        float keep = hi ? v[i + CNT] : v[i]; \
        float send = hi ? v[i] : v[i + CNT]; \
        v[i] = keep + __shfl_xor(send, MASK); } }
        RSTEP(16, 16) RSTEP(8, 8) RSTEP(4, 4) RSTEP(2, 2) RSTEP(1, 1)
#undef RSTEP

        int j  = kk >> 3;
        int bc = kk & 7;
        int l  = l0 + lq * 4 + j;
        if (l < LMAX) {
            float rv = (l < m) ? 0.f : v[0];
            out[(bc * LMAX + l) * MMAX + m] = rv;
        }
    }
}

// ---------------- legacy fallback (cplx hedge / small ws) ----------------
template<int CPLX>
__global__ __launch_bounds__(192) void k_dft_leg(const float* __restrict__ x,
                                                 float* __restrict__ xt,
                                                 int mb, int mc) {
    const int k    = blockIdx.x;
    const int half = blockIdx.y;
    const int tid  = threadIdx.x;

    __shared__ __align__(16) float  xr[8 * 724];
    __shared__ __align__(16) float2 exo[8 * 362];

    {
        const float4* __restrict__ x4 = (const float4*)x;
        for (int j = tid; j < 8 * 180; j += 192) {
            int b = j / 180, q = j - b * 180;
            ((float4*)&xr[b * 724])[q] = x4[(b * NLAT + k) * 180 + q];
        }
        if (tid < 8) ((float4*)&xr[tid * 724])[180] = make_float4(0.f, 0.f, 0.f, 0.f);
    }
    __syncthreads();

    for (int j = tid; j < 8 * NLAT; j += 192) {
        int b = j / NLAT, n = j - b * NLAT;
        float xa  = xr[b * 724 + n];
        float xbv = xr[b * 724 + (NLON - n)];
        exo[b * 362 + n] = make_float2(xa + xbv, xa - xbv);
    }
    __syncthreads();

    const int  m_local = half * 192 + tid;
    const bool valid   = (m_local < mc);
    const int  m       = mb + (valid ? m_local : 0);

    float aRe[8], aIm[8];
#pragma unroll
    for (int b = 0; b < 8; ++b) { aRe[b] = 0.f; aIm[b] = 0.f; }

    int tacc = 0;
    for (int n = 0; n < NLAT; ++n) {
        float sn, cs;
        __sincosf((float)tacc * kAngF, &sn, &cs);
        float wgt = (n == 360) ? 0.5f : 1.0f;
        float fc = wgt * kAngF * cs;
        float fs = -wgt * kAngF * sn;
        tacc += m;
        if (tacc >= NLON) tacc -= NLON;
#pragma unroll
        for (int b = 0; b < 8; ++b) {
            float2 e = exo[b * 362 + n];
            aRe[b] += fc * e.x;
            if (CPLX) aIm[b] += fs * e.y;
        }
    }

    if (valid) {
        float4* __restrict__ xt4 = (float4*)xt;
        if (CPLX) {
            int base = (m_local * NLAT + k) * 4;
#pragma unroll
            for (int q = 0; q < 4; ++q)
                xt4[base + q] = make_float4(aRe[2*q], aIm[2*q], aRe[2*q+1], aIm[2*q+1]);
        } else {
            int base = (m_local * NLAT + k) * 2;
            xt4[base + 0] = make_float4(aRe[0], aRe[1], aRe[2], aRe[3]);
            xt4[base + 1] = make_float4(aRe[4], aRe[5], aRe[6], aRe[7]);
        }
    }
}

template<int CPLX>
__global__ __launch_bounds__(256) void k_contract_leg(const float* __restrict__ W,
                                                      const float* __restrict__ xt,
                                                      float* __restrict__ out,
                                                      int mb) {
    const int lt   = blockIdx.x;
    const int mloc = blockIdx.y;
    const int m    = mb + mloc;
    const int l0   = lt * 32;
    const int tid  = threadIdx.x;

    if (l0 + 31 < m) {
        int l = l0 + (tid >> 3), bc = tid & 7;
        int idx = (bc * LMAX + l) * MMAX + m;
        if (CPLX) ((float2*)out)[idx] = make_float2(0.f, 0.f);
        else      out[idx] = 0.f;
        return;
    }

    const int kk = tid & 31, lq = tid >> 5;
    const int lb = l0 + lq * 4;

    int lr[4];
#pragma unroll
    for (int j = 0; j < 4; ++j) {
        int l = lb + j;
        if (l < m)        l = m;
        if (l > LMAX - 1) l = LMAX - 1;
        lr[j] = l;
    }

    const float* __restrict__ Wm = W + (size_t)m * (LMAX * NLAT);
    const float4* __restrict__ xt4 = (const float4*)xt;
    constexpr int NX = CPLX ? 4 : 2;
    constexpr int NV = CPLX ? 64 : 32;

    float v[NV];
#pragma unroll
    for (int i = 0; i < NV; ++i) v[i] = 0.f;

#define CLOAD(T, WV, XV) { \
    int kq = (T) * 32 + kk; \
    int kc = (kq < NLAT) ? kq : (NLAT - 1); \
    _Pragma("unroll") \
    for (int j = 0; j < 4; ++j) WV[j] = Wm[lr[j] * NLAT + kc]; \
    int xb = (mloc * NLAT + kc) * NX; \
    _Pragma("unroll") \
    for (int q = 0; q < NX; ++q) XV[q] = xt4[xb + q]; \
    if (kq >= NLAT) { WV[0] = WV[1] = WV[2] = WV[3] = 0.f; } }

#define CFMA(WV, XV) { \
    _Pragma("unroll") \
    for (int j = 0; j < 4; ++j) { \
        float wj = WV[j]; \
        if (CPLX) { \
            _Pragma("unroll") \
            for (int q = 0; q < 4; ++q) { \
                v[j*16 + (2*q  )*2 + 0] += wj * XV[q].x; \
                v[j*16 + (2*q  )*2 + 1] += wj * XV[q].y; \
                v[j*16 + (2*q+1)*2 + 0] += wj * XV[q].z; \
                v[j*16 + (2*q+1)*2 + 1] += wj * XV[q].w; \
            } \
        } else { \
            v[j*8 + 0] += wj * XV[0].x;  v[j*8 + 1] += wj * XV[0].y; \
            v[j*8 + 2] += wj * XV[0].z;  v[j*8 + 3] += wj * XV[0].w; \
            v[j*8 + 4] += wj * XV[1].x;  v[j*8 + 5] += wj * XV[1].y; \
            v[j*8 + 6] += wj * XV[1].z;  v[j*8 + 7] += wj * XV[1].w; \
        } \
    } }

    float  w0[4], w1[4], wn[4];
    float4 x0[NX], x1[NX], xn[NX];
    CLOAD(0, w0, x0)
    CLOAD(1, w1, x1)
#pragma unroll
    for (int t = 0; t < 12; ++t) {
        if (t < 10) CLOAD(t + 2, wn, xn)
        CFMA(w0, x0)
#pragma unroll
        for (int j = 0; j < 4; ++j) w0[j] = w1[j];
#pragma unroll
        for (int q = 0; q < NX; ++q) x0[q] = x1[q];
        if (t < 10) {
#pragma unroll
            for (int j = 0; j < 4; ++j) w1[j] = wn[j];
#pragma unroll
            for (int q = 0; q < NX; ++q) x1[q] = xn[q];
        }
    }
#undef CLOAD
#undef CFMA

#define RSTEP(MASK, CNT) { const bool hi = (kk & MASK) != 0; \
    _Pragma("unroll") \
    for (int i = 0; i < CNT; ++i) { \
        float keep = hi ? v[i + CNT] : v[i]; \
        float send = hi ? v[i] : v[i + CNT]; \
        v[i] = keep + __shfl_xor(send, MASK); } }
    if (CPLX) {
        RSTEP(16, 32) RSTEP(8, 16) RSTEP(4, 8) RSTEP(2, 4) RSTEP(1, 2)
    } else {
        RSTEP(16, 16) RSTEP(8, 8) RSTEP(4, 4) RSTEP(2, 2) RSTEP(1, 1)
    }
#undef RSTEP

    int j  = kk >> 3;
    int bc = kk & 7;
    int l  = l0 + lq * 4 + j;
    if (l >= LMAX) return;
    int idx = (bc * LMAX + l) * MMAX + m;
    if (CPLX) {
        float2 r = make_float2(v[0], v[1]);
        if (l < m) r = make_float2(0.f, 0.f);
        ((float2*)out)[idx] = r;
    } else {
        float r = (l < m) ? 0.f : v[0];
        out[idx] = r;
    }
}

extern "C" void kernel_launch(void* const* d_in, const int* in_sizes, int n_in,
                              void* d_out, int out_size, void* d_ws, size_t ws_size,
                              hipStream_t stream) {
    const float* x = (const float*)d_in[0];
    const float* W = (const float*)d_in[1];
    float* ws = (float*)d_ws;

    const int n_complex = 8 * LMAX * MMAX;            // 1,039,680
    const int cplx = (out_size >= 2 * n_complex) ? 1 : 0;

    if (!cplx && ws_size >= (size_t)(NSL + 1) * SL_F * sizeof(float)) {
        float* slices = ws;
        float* xt     = ws + (size_t)NSL * SL_F;
        k_dft9<<<dim3(181, NSL / 2), dim3(256), 0, stream>>>(x, slices, DFT_REP);
        k_redT<<<dim3(23, 12), dim3(256), 0, stream>>>(slices, xt, RED_REP);
        k_contract4<<<dim3(12, MMAX), dim3(256), 0, stream>>>(W, xt, (float*)d_out,
                                                              CON_REP);
        return;
    }

    // hedge / fallback: legacy sincosf path (chunked if ws small)
    const int xs_per_mk = cplx ? 16 : 8;
    const size_t per_m_bytes = (size_t)NLAT * xs_per_mk * sizeof(float);
    int CM = (int)(ws_size / per_m_bytes);
    if (CM > MMAX) CM = MMAX;
    if (CM < 1)    CM = 1;
    for (int mbase = 0; mbase < MMAX; mbase += CM) {
        int mc = MMAX - mbase;
        if (mc > CM) mc = CM;
        if (cplx) {
            k_dft_leg<1><<<dim3(NLAT, (mc + 191) / 192), dim3(192), 0, stream>>>(
                x, ws, mbase, mc);
            k_contract_leg<1><<<dim3(12, mc), dim3(256), 0, stream>>>(W, ws, (float*)d_out, mbase);
        } else {
            k_dft_leg<0><<<dim3(NLAT, (mc + 191) / 192), dim3(192), 0, stream>>>(
                x, ws, mbase, mc);
            k_contract_leg<0><<<dim3(12, mc), dim3(256), 0, stream>>>(W, ws, (float*)d_out, mbase);
        }
    }
}

// Round 18
// 56.481 us; speedup vs baseline: 12.5003x; 12.5003x over previous
//
#include <hip/hip_runtime.h>

#define NLAT 361
#define NLON 720
#define LMAX 360
#define MMAX 361

#define NSL  8                         // n slices
#define QSL  46                        // slice width (slice 7: 39)
#define SL_F (NLAT * MMAX * 8)         // 1,042,568 floats per slice

static constexpr float kAngF = 8.72664625997164788e-3f;  // 2*pi/720

// ---------------- kernel 1: DFT ----------------
// block 256 = 4 waves = (2 k-slots) x (2 n-halves); wave = 64 m-lanes x 6 m.
// slice[nq][k][m][8ch] = sum_{n in slice} cos(n*m*th)*(x[n]+x[720-n])
// launch_bounds(256,1): grid-limited occupancy (724 blocks), so let the
// allocator keep acc[6][8]+recurrence state live without spilling.
__global__ __launch_bounds__(256, 1) void k_dft9(const float* __restrict__ x,
                                                 float* __restrict__ slices) {
    const int bx  = blockIdx.x;
    const int by  = blockIdx.y;
    const int tid = threadIdx.x;
    const int w   = tid >> 6;          // wave 0..3
    const int ks  = w & 1;             // k slot
    const int nh  = w >> 1;            // n half
    const int ml  = tid & 63;          // m lane

    __shared__ __align__(16) float xe[2][2 * QSL][8];

    const int nq  = by * 2 + nh;
    const int n0  = nq * QSL;
    const int cnt = (n0 < NLAT) ? min(QSL, NLAT - n0) : 0;
    const int rb  = nh * QSL;
    const int k   = bx * 2 + ks;

    for (int j = tid; j < 2 * 8 * (2 * QSL); j += 256) {
        int s   = j / (8 * 2 * QSL);
        int rr  = j - s * (8 * 2 * QSL);
        int ch  = rr / (2 * QSL);
        int nnb = rr - ch * (2 * QSL);
        int n   = by * (2 * QSL) + nnb;
        int kq  = bx * 2 + s; if (kq > 360) kq = 360;
        float v = 0.f;
        if (n <= 360) {
            const float* __restrict__ row = x + ((size_t)ch * NLAT + kq) * NLON;
            float a = row[n];
            float b = (n == 0) ? 0.f : row[NLON - n];   // n=360 -> 2x; fixup below
            v = a + b;
        }
        xe[s][nnb][ch] = v;
    }
    __syncthreads();

    float P0[6], P1[6], c2[6];
#pragma unroll
    for (int q = 0; q < 6; ++q) {
        int m = ml + 64 * q; if (m > 360) m = 360;      // clamp; store guarded
        int t0 = (n0 * m) % NLON;                       // exact integer reduction
        int t1 = t0 + m; if (t1 >= NLON) t1 -= NLON;
        P0[q] = __cosf((float)t0 * kAngF);
        P1[q] = __cosf((float)t1 * kAngF);
        c2[q] = 2.f * __cosf((float)m * kAngF);
    }

    float acc[6][8];
#pragma unroll
    for (int q = 0; q < 6; ++q)
#pragma unroll
        for (int b = 0; b < 8; ++b) acc[q][b] = 0.f;

#pragma unroll 2
    for (int nn = 0; nn < cnt; ++nn) {
        float4 e0 = *(const float4*)&xe[ks][rb + nn][0];    // uniform broadcast
        float4 e1 = *(const float4*)&xe[ks][rb + nn][4];
#pragma unroll
        for (int q = 0; q < 6; ++q) {
            float f = P0[q];
            acc[q][0] += f * e0.x;  acc[q][1] += f * e0.y;
            acc[q][2] += f * e0.z;  acc[q][3] += f * e0.w;
            acc[q][4] += f * e1.x;  acc[q][5] += f * e1.y;
            acc[q][6] += f * e1.z;  acc[q][7] += f * e1.w;
            float Pn = c2[q] * P1[q] - P0[q];
            P0[q] = P1[q];
            P1[q] = Pn;
        }
    }

    if (nq == NSL - 1) {     // n=360 (nn=38): weight 1*(-1)^m*(2x) -> 0.5
        float4 e0 = *(const float4*)&xe[ks][rb + 38][0];
        float4 e1 = *(const float4*)&xe[ks][rb + 38][4];
#pragma unroll
        for (int q = 0; q < 6; ++q) {
            int m = ml + 64 * q;
            float h = 0.5f * ((m & 1) ? -1.f : 1.f);
            acc[q][0] -= h * e0.x;  acc[q][1] -= h * e0.y;
            acc[q][2] -= h * e0.z;  acc[q][3] -= h * e0.w;
            acc[q][4] -= h * e1.x;  acc[q][5] -= h * e1.y;
            acc[q][6] -= h * e1.z;  acc[q][7] -= h * e1.w;
        }
    }

    if (k <= 360) {
        float* __restrict__ sl = slices + (size_t)nq * SL_F;
#pragma unroll
        for (int q = 0; q < 6; ++q) {
            int m = ml + 64 * q;
            if (m > 360) continue;
            float4* o = (float4*)(sl + ((size_t)k * MMAX + m) * 8);
            o[0] = make_float4(acc[q][0] * kAngF, acc[q][1] * kAngF,
                               acc[q][2] * kAngF, acc[q][3] * kAngF);
            o[1] = make_float4(acc[q][4] * kAngF, acc[q][5] * kAngF,
                               acc[q][6] * kAngF, acc[q][7] * kAngF);
        }
    }
}

// ---------------- kernel 2: sum NSL slices + transpose [k][m] -> [m][k] --------
#define TK 16
#define TM 32
#define TSTRIDE 265
__global__ __launch_bounds__(256) void k_redT(const float* __restrict__ slices,
                                              float* __restrict__ xt) {
    const int k0  = blockIdx.x * TK;
    const int m0  = blockIdx.y * TM;
    const int tid = threadIdx.x;

    __shared__ __align__(16) float t[TK * TSTRIDE];

    for (int j = tid; j < TK * TM * 2; j += 256) {
        int kk = j / (TM * 2);
        int rr = j - kk * (TM * 2);
        int mm = rr >> 1, h = rr & 1;
        int k = k0 + kk, m = m0 + mm;
        float4 s = make_float4(0.f, 0.f, 0.f, 0.f);
        if (k <= 360 && m <= 360) {
            size_t off = ((size_t)k * MMAX + m) * 2 + h;
            const float4* p = (const float4*)slices;
#pragma unroll
            for (int q = 0; q < NSL; ++q) {
                float4 a = p[off + (size_t)q * (SL_F / 4)];
                s.x += a.x; s.y += a.y; s.z += a.z; s.w += a.w;
            }
        }
        *(float4*)&t[kk * TSTRIDE + mm * 8 + h * 4] = s;
    }
    __syncthreads();

    for (int j = tid; j < TM * TK * 2; j += 256) {
        int mm = j / (TK * 2);
        int rr = j - mm * (TK * 2);
        int kk = rr >> 1, h = rr & 1;
        int k = k0 + kk, m = m0 + mm;
        if (k <= 360 && m <= 360) {
            float4 v = *(const float4*)&t[kk * TSTRIDE + mm * 8 + h * 4];
            ((float4*)xt)[((size_t)m * MMAX + k) * 2 + h] = v;
        }
    }
}

// ---------------- kernel 3: contraction ----------------
// launch_bounds(256,1): the whole point — let wv[12][4] (48 regs) stay LIVE so
// all 48 W loads are actually in flight (R17 showed VGPR=64 -> serialized).
__global__ __launch_bounds__(256, 1) void k_contract4(const float* __restrict__ W,
                                                      const float* __restrict__ xt,
                                                      float* __restrict__ out) {
    const int lt   = blockIdx.x;
    const int m    = blockIdx.y;
    const int l0   = lt * 32;
    const int tid  = threadIdx.x;

    if (l0 + 31 < m) {
        int l = l0 + (tid >> 3), bc = tid & 7;
        out[(bc * LMAX + l) * MMAX + m] = 0.f;
        return;
    }

    const int kk = tid & 31, lq = tid >> 5;
    const int lb = l0 + lq * 4;

    int lr[4];
#pragma unroll
    for (int j = 0; j < 4; ++j) {
        int l = lb + j;
        if (l < m)        l = m;
        if (l > LMAX - 1) l = LMAX - 1;
        lr[j] = l;
    }

    const float* __restrict__ Wm = W + (size_t)m * (LMAX * NLAT);
    const float* __restrict__ r0 = Wm + lr[0] * NLAT + kk;
    const float* __restrict__ r1 = Wm + lr[1] * NLAT + kk;
    const float* __restrict__ r2 = Wm + lr[2] * NLAT + kk;
    const float* __restrict__ r3 = Wm + lr[3] * NLAT + kk;

    float wv[12][4];
#pragma unroll
    for (int t = 0; t < 11; ++t) {
        wv[t][0] = r0[t * 32];
        wv[t][1] = r1[t * 32];
        wv[t][2] = r2[t * 32];
        wv[t][3] = r3[t * 32];
    }
    {
        int kq = 11 * 32 + kk;
        int kc = (kq <= 360) ? kq : 360;
        wv[11][0] = Wm[lr[0] * NLAT + kc];
        wv[11][1] = Wm[lr[1] * NLAT + kc];
        wv[11][2] = Wm[lr[2] * NLAT + kc];
        wv[11][3] = Wm[lr[3] * NLAT + kc];
        if (kq > 360) { wv[11][0] = wv[11][1] = wv[11][2] = wv[11][3] = 0.f; }
    }

    float v[32];
#pragma unroll
    for (int i = 0; i < 32; ++i) v[i] = 0.f;

    const float4* __restrict__ xt4 = (const float4*)xt;
#pragma unroll
    for (int t = 0; t < 12; ++t) {
        int kq = t * 32 + kk;
        int kc = (kq <= 360) ? kq : 360;
        int xb = (m * NLAT + kc) * 2;
        float4 x0 = xt4[xb], x1 = xt4[xb + 1];
#pragma unroll
        for (int j = 0; j < 4; ++j) {
            float wj = wv[t][j];
            v[j*8 + 0] += wj * x0.x;  v[j*8 + 1] += wj * x0.y;
            v[j*8 + 2] += wj * x0.z;  v[j*8 + 3] += wj * x0.w;
            v[j*8 + 4] += wj * x1.x;  v[j*8 + 5] += wj * x1.y;
            v[j*8 + 6] += wj * x1.z;  v[j*8 + 7] += wj * x1.w;
        }
    }

#define RSTEP(MASK, CNT) { const bool hi = (kk & MASK) != 0; \
    _Pragma("unroll") \
    for (int i = 0; i < CNT; ++i) { \
        float keep = hi ? v[i + CNT] : v[i]; \
        float send = hi ? v[i] : v[i + CNT]; \
        v[i] = keep + __shfl_xor(send, MASK); } }
    RSTEP(16, 16) RSTEP(8, 8) RSTEP(4, 4) RSTEP(2, 2) RSTEP(1, 1)
#undef RSTEP

    int j  = kk >> 3;
    int bc = kk & 7;
    int l  = l0 + lq * 4 + j;
    if (l >= LMAX) return;
    float r = (l < m) ? 0.f : v[0];
    out[(bc * LMAX + l) * MMAX + m] = r;
}

// ---------------- legacy fallback (cplx hedge / small ws) ----------------
template<int CPLX>
__global__ __launch_bounds__(192) void k_dft_leg(const float* __restrict__ x,
                                                 float* __restrict__ xt,
                                                 int mb, int mc) {
    const int k    = blockIdx.x;
    const int half = blockIdx.y;
    const int tid  = threadIdx.x;

    __shared__ __align__(16) float  xr[8 * 724];
    __shared__ __align__(16) float2 exo[8 * 362];

    {
        const float4* __restrict__ x4 = (const float4*)x;
        for (int j = tid; j < 8 * 180; j += 192) {
            int b = j / 180, q = j - b * 180;
            ((float4*)&xr[b * 724])[q] = x4[(b * NLAT + k) * 180 + q];
        }
        if (tid < 8) ((float4*)&xr[tid * 724])[180] = make_float4(0.f, 0.f, 0.f, 0.f);
    }
    __syncthreads();

    for (int j = tid; j < 8 * NLAT; j += 192) {
        int b = j / NLAT, n = j - b * NLAT;
        float xa  = xr[b * 724 + n];
        float xbv = xr[b * 724 + (NLON - n)];
        exo[b * 362 + n] = make_float2(xa + xbv, xa - xbv);
    }
    __syncthreads();

    const int  m_local = half * 192 + tid;
    const bool valid   = (m_local < mc);
    const int  m       = mb + (valid ? m_local : 0);

    float aRe[8], aIm[8];
#pragma unroll
    for (int b = 0; b < 8; ++b) { aRe[b] = 0.f; aIm[b] = 0.f; }

    int tacc = 0;
    for (int n = 0; n < NLAT; ++n) {
        float sn, cs;
        __sincosf((float)tacc * kAngF, &sn, &cs);
        float wgt = (n == 360) ? 0.5f : 1.0f;
        float fc = wgt * kAngF * cs;
        float fs = -wgt * kAngF * sn;
        tacc += m;
        if (tacc >= NLON) tacc -= NLON;
#pragma unroll
        for (int b = 0; b < 8; ++b) {
            float2 e = exo[b * 362 + n];
            aRe[b] += fc * e.x;
            if (CPLX) aIm[b] += fs * e.y;
        }
    }

    if (valid) {
        float4* __restrict__ xt4 = (float4*)xt;
        if (CPLX) {
            int base = (m_local * NLAT + k) * 4;
#pragma unroll
            for (int q = 0; q < 4; ++q)
                xt4[base + q] = make_float4(aRe[2*q], aIm[2*q], aRe[2*q+1], aIm[2*q+1]);
        } else {
            int base = (m_local * NLAT + k) * 2;
            xt4[base + 0] = make_float4(aRe[0], aRe[1], aRe[2], aRe[3]);
            xt4[base + 1] = make_float4(aRe[4], aRe[5], aRe[6], aRe[7]);
        }
    }
}

template<int CPLX>
__global__ __launch_bounds__(256) void k_contract_leg(const float* __restrict__ W,
                                                      const float* __restrict__ xt,
                                                      float* __restrict__ out,
                                                      int mb) {
    const int lt   = blockIdx.x;
    const int mloc = blockIdx.y;
    const int m    = mb + mloc;
    const int l0   = lt * 32;
    const int tid  = threadIdx.x;

    if (l0 + 31 < m) {
        int l = l0 + (tid >> 3), bc = tid & 7;
        int idx = (bc * LMAX + l) * MMAX + m;
        if (CPLX) ((float2*)out)[idx] = make_float2(0.f, 0.f);
        else      out[idx] = 0.f;
        return;
    }

    const int kk = tid & 31, lq = tid >> 5;
    const int lb = l0 + lq * 4;

    int lr[4];
#pragma unroll
    for (int j = 0; j < 4; ++j) {
        int l = lb + j;
        if (l < m)        l = m;
        if (l > LMAX - 1) l = LMAX - 1;
        lr[j] = l;
    }

    const float* __restrict__ Wm = W + (size_t)m * (LMAX * NLAT);
    const float4* __restrict__ xt4 = (const float4*)xt;
    constexpr int NX = CPLX ? 4 : 2;
    constexpr int NV = CPLX ? 64 : 32;

    float v[NV];
#pragma unroll
    for (int i = 0; i < NV; ++i) v[i] = 0.f;

#define CLOAD(T, WV, XV) { \
    int kq = (T) * 32 + kk; \
    int kc = (kq < NLAT) ? kq : (NLAT - 1); \
    _Pragma("unroll") \
    for (int j = 0; j < 4; ++j) WV[j] = Wm[lr[j] * NLAT + kc]; \
    int xb = (mloc * NLAT + kc) * NX; \
    _Pragma("unroll") \
    for (int q = 0; q < NX; ++q) XV[q] = xt4[xb + q]; \
    if (kq >= NLAT) { WV[0] = WV[1] = WV[2] = WV[3] = 0.f; } }

#define CFMA(WV, XV) { \
    _Pragma("unroll") \
    for (int j = 0; j < 4; ++j) { \
        float wj = WV[j]; \
        if (CPLX) { \
            _Pragma("unroll") \
            for (int q = 0; q < 4; ++q) { \
                v[j*16 + (2*q  )*2 + 0] += wj * XV[q].x; \
                v[j*16 + (2*q  )*2 + 1] += wj * XV[q].y; \
                v[j*16 + (2*q+1)*2 + 0] += wj * XV[q].z; \
                v[j*16 + (2*q+1)*2 + 1] += wj * XV[q].w; \
            } \
        } else { \
            v[j*8 + 0] += wj * XV[0].x;  v[j*8 + 1] += wj * XV[0].y; \
            v[j*8 + 2] += wj * XV[0].z;  v[j*8 + 3] += wj * XV[0].w; \
            v[j*8 + 4] += wj * XV[1].x;  v[j*8 + 5] += wj * XV[1].y; \
            v[j*8 + 6] += wj * XV[1].z;  v[j*8 + 7] += wj * XV[1].w; \
        } \
    } }

    float  w0[4], w1[4], wn[4];
    float4 x0[NX], x1[NX], xn[NX];
    CLOAD(0, w0, x0)
    CLOAD(1, w1, x1)
#pragma unroll
    for (int t = 0; t < 12; ++t) {
        if (t < 10) CLOAD(t + 2, wn, xn)
        CFMA(w0, x0)
#pragma unroll
        for (int j = 0; j < 4; ++j) w0[j] = w1[j];
#pragma unroll
        for (int q = 0; q < NX; ++q) x0[q] = x1[q];
        if (t < 10) {
#pragma unroll
            for (int j = 0; j < 4; ++j) w1[j] = wn[j];
#pragma unroll
            for (int q = 0; q < NX; ++q) x1[q] = xn[q];
        }
    }
#undef CLOAD
#undef CFMA

#define RSTEP(MASK, CNT) { const bool hi = (kk & MASK) != 0; \
    _Pragma("unroll") \
    for (int i = 0; i < CNT; ++i) { \
        float keep = hi ? v[i + CNT] : v[i]; \
        float send = hi ? v[i] : v[i + CNT]; \
        v[i] = keep + __shfl_xor(send, MASK); } }
    if (CPLX) {
        RSTEP(16, 32) RSTEP(8, 16) RSTEP(4, 8) RSTEP(2, 4) RSTEP(1, 2)
    } else {
        RSTEP(16, 16) RSTEP(8, 8) RSTEP(4, 4) RSTEP(2, 2) RSTEP(1, 1)
    }
#undef RSTEP

    int j  = kk >> 3;
    int bc = kk & 7;
    int l  = l0 + lq * 4 + j;
    if (l >= LMAX) return;
    int idx = (bc * LMAX + l) * MMAX + m;
    if (CPLX) {
        float2 r = make_float2(v[0], v[1]);
        if (l < m) r = make_float2(0.f, 0.f);
        ((float2*)out)[idx] = r;
    } else {
        float r = (l < m) ? 0.f : v[0];
        out[idx] = r;
    }
}

extern "C" void kernel_launch(void* const* d_in, const int* in_sizes, int n_in,
                              void* d_out, int out_size, void* d_ws, size_t ws_size,
                              hipStream_t stream) {
    const float* x = (const float*)d_in[0];
    const float* W = (const float*)d_in[1];
    float* ws = (float*)d_ws;

    const int n_complex = 8 * LMAX * MMAX;            // 1,039,680
    const int cplx = (out_size >= 2 * n_complex) ? 1 : 0;

    if (!cplx && ws_size >= (size_t)(NSL + 1) * SL_F * sizeof(float)) {
        float* slices = ws;
        float* xt     = ws + (size_t)NSL * SL_F;
        k_dft9<<<dim3(181, NSL / 2), dim3(256), 0, stream>>>(x, slices);
        k_redT<<<dim3(23, 12), dim3(256), 0, stream>>>(slices, xt);
        k_contract4<<<dim3(12, MMAX), dim3(256), 0, stream>>>(W, xt, (float*)d_out);
        return;
    }

    // hedge / fallback: legacy sincosf path (chunked if ws small)
    const int xs_per_mk = cplx ? 16 : 8;
    const size_t per_m_bytes = (size_t)NLAT * xs_per_mk * sizeof(float);
    int CM = (int)(ws_size / per_m_bytes);
    if (CM > MMAX) CM = MMAX;
    if (CM < 1)    CM = 1;
    for (int mbase = 0; mbase < MMAX; mbase += CM) {
        int mc = MMAX - mbase;
        if (mc > CM) mc = CM;
        if (cplx) {
            k_dft_leg<1><<<dim3(NLAT, (mc + 191) / 192), dim3(192), 0, stream>>>(
                x, ws, mbase, mc);
            k_contract_leg<1><<<dim3(12, mc), dim3(256), 0, stream>>>(W, ws, (float*)d_out, mbase);
        } else {
            k_dft_leg<0><<<dim3(NLAT, (mc + 191) / 192), dim3(192), 0, stream>>>(
                x, ws, mbase, mc);
            k_contract_leg<0><<<dim3(12, mc), dim3(256), 0, stream>>>(W, ws, (float*)d_out, mbase);
        }
    }
}